// Round 9
// baseline (96.377 us; speedup 1.0000x reference)
//
#include <hip/hip_runtime.h>
#include <stdint.h>

#define SEQ 2048
#define DM 1024
#define NH 16
#define DH 64
#define LN_EPS 1e-5f

typedef __bf16 bf16x8 __attribute__((ext_vector_type(8)));
typedef float f32x4 __attribute__((ext_vector_type(4)));
typedef unsigned short u16;
typedef unsigned short u16x8 __attribute__((ext_vector_type(8)));
typedef unsigned int u32;
typedef short s16x4 __attribute__((ext_vector_type(4)));

__device__ __forceinline__ u16 f2bf(float f) {
  unsigned int u = __float_as_uint(f);
  unsigned int r = (u + 0x7fffu + ((u >> 16) & 1u)) >> 16;
  return (u16)r;
}

__device__ __forceinline__ float bf2f(u16 x) {
  return __uint_as_float(((u32)x) << 16);
}

__device__ __forceinline__ u32 packbf(float a, float b) {
  union { __bf16 h[2]; u32 u; } pw;
  pw.h[0] = (__bf16)a; pw.h[1] = (__bf16)b;
  return pw.u;
}

// 16x16x16 bf16 MFMA (2-reg A/B). Builtin if present, else inline asm.
__device__ __forceinline__ f32x4 mfma16x16x16bf(s16x4 a, s16x4 b, f32x4 c) {
#if __has_builtin(__builtin_amdgcn_mfma_f32_16x16x16bf16_1k)
  return __builtin_amdgcn_mfma_f32_16x16x16bf16_1k(a, b, c, 0, 0, 0);
#else
  asm("v_mfma_f32_16x16x16_bf16 %0, %1, %2, %0" : "+v"(c) : "v"(a), "v"(b));
  return c;
#endif
}

#define GLD_LDS16(gp, lp) __builtin_amdgcn_global_load_lds( \
  (const __attribute__((address_space(1))) void*)(gp),      \
  (__attribute__((address_space(3))) void*)(lp), 16, 0, 0)

// ---------------- fused f32 -> bf16 convert (h, Wqkv, Wout in one launch) ----
__global__ __launch_bounds__(256)
void k_f2bf3(const float* __restrict__ a, u16* __restrict__ oa, int na,
             const float* __restrict__ b, u16* __restrict__ ob, int nb,
             const float* __restrict__ c, u16* __restrict__ oc, int nc) {
  int i = blockIdx.x * 256 + threadIdx.x;
  const float* src;
  u16* dst;
  if (i < na) { src = a; dst = oa; }
  else if (i < na + nb) { src = b; dst = ob; i -= na; }
  else if (i < na + nb + nc) { src = c; dst = oc; i -= na + nb; }
  else return;
  float4 v = reinterpret_cast<const float4*>(src)[i];
  ushort4 o;
  o.x = f2bf(v.x); o.y = f2bf(v.y); o.z = f2bf(v.z); o.w = f2bf(v.w);
  reinterpret_cast<ushort4*>(dst)[i] = o;
}

// ---------------- GEMM: C = A(bf16 MxK) * B(bf16 NxK)^T ----------------
// 4 waves 2x2; wave tile (BM/2)x(BN/2). Optional split-K via gridDim.z.
// EPI 2: QKV split: n<2048 -> outb[m][n]; n>=2048 -> outv[(n-2048)][m] (V^T).
// EPI 3: bf16 partials to outb[z][m][n] (no bias).
// XCDW: x-blocks per XCD chunk for L2 locality remap (0 = no remap).
template <int EPI, int BM, int BN, int XCDW>
__global__ __launch_bounds__(256)
void k_gemm_bt(const u16* __restrict__ A, const u16* __restrict__ B,
               const float* __restrict__ bias,
               u16* __restrict__ outb, u16* __restrict__ outv,
               int M, int N, int K) {
  constexpr int MF = BM / 32, NF = BN / 32;
  constexpr int WM = BM / 2, WN = BN / 2;
  constexpr int AG = BM / 64, BG = BN / 64;
  __shared__ u16 Alds[2][BM][32];
  __shared__ u16 Blds[2][BN][32];
  const int tid = threadIdx.x;
  const int w = tid >> 6, l = tid & 63, lg = l >> 4, lr = l & 15;
  const int wr = w >> 1, wc = w & 1;

  int bx = blockIdx.x, by = blockIdx.y, bz = blockIdx.z;
  if (XCDW > 0) {
    // bijective: XCD k owns x in [k*XCDW, (k+1)*XCDW), all y, all z
    const int nx = gridDim.x, ny = gridDim.y;
    const int u = bx + nx * (by + ny * bz);
    const int xcd = u & 7, g = u >> 3;
    bx = xcd * XCDW + (g % XCDW);
    const int rem = g / XCDW;
    by = rem % ny;
    bz = rem / ny;
  }

  const int m0 = by * BM, n0 = bx * BN;
  const int KTall = K >> 5;
  const int ktn = KTall / gridDim.z;
  const int kt0 = bz * ktn;

  f32x4 acc[MF][NF] = {};

  auto stage = [&](int buf, int kt) {
    const int k0 = kt << 5;
    const int row = l >> 2, col = (l & 3) * 8;
#pragma unroll
    for (int p = 0; p < AG; ++p) {
      const int rbase = (w * AG + p) * 16;
      GLD_LDS16(A + (size_t)(m0 + rbase + row) * K + k0 + col, &Alds[buf][rbase][0]);
    }
#pragma unroll
    for (int p = 0; p < BG; ++p) {
      const int rbase = (w * BG + p) * 16;
      GLD_LDS16(B + (size_t)(n0 + rbase + row) * K + k0 + col, &Blds[buf][rbase][0]);
    }
  };

  auto compute = [&](int buf) {
    bf16x8 af[MF], bfr[NF];
#pragma unroll
    for (int mi = 0; mi < MF; ++mi)
      af[mi] = *reinterpret_cast<const bf16x8*>(&Alds[buf][wr * WM + mi * 16 + lr][lg * 8]);
#pragma unroll
    for (int ni = 0; ni < NF; ++ni)
      bfr[ni] = *reinterpret_cast<const bf16x8*>(&Blds[buf][wc * WN + ni * 16 + lr][lg * 8]);
#pragma unroll
    for (int mi = 0; mi < MF; ++mi)
#pragma unroll
      for (int ni = 0; ni < NF; ++ni)
        acc[mi][ni] = __builtin_amdgcn_mfma_f32_16x16x32_bf16(af[mi], bfr[ni], acc[mi][ni], 0, 0, 0);
  };

  stage(0, kt0);
  __syncthreads();
  for (int i = 0; i < ktn; ++i) {
    const int cur = i & 1;
    if (i + 1 < ktn) stage(cur ^ 1, kt0 + i + 1);
    compute(cur);
    __syncthreads();
  }

  if (EPI == 3) {
    u16* op = outb + (size_t)bz * M * N;
#pragma unroll
    for (int ni = 0; ni < NF; ++ni) {
      const int n = n0 + wc * WN + ni * 16 + lr;
#pragma unroll
      for (int mi = 0; mi < MF; ++mi) {
#pragma unroll
        for (int r = 0; r < 4; ++r) {
          const int m = m0 + wr * WM + mi * 16 + lg * 4 + r;
          op[(size_t)m * N + n] = f2bf(acc[mi][ni][r]);
        }
      }
    }
  } else {  // EPI == 2
    if (n0 < 2048) {
#pragma unroll
      for (int ni = 0; ni < NF; ++ni) {
        const int n = n0 + wc * WN + ni * 16 + lr;
        const float bn = bias[n];
#pragma unroll
        for (int mi = 0; mi < MF; ++mi) {
#pragma unroll
          for (int r = 0; r < 4; ++r) {
            const int m = m0 + wr * WM + mi * 16 + lg * 4 + r;
            outb[(size_t)m * 2048 + n] = f2bf(acc[mi][ni][r] + bn);
          }
        }
      }
    } else {
#pragma unroll
      for (int ni = 0; ni < NF; ++ni) {
        const int n = n0 + wc * WN + ni * 16 + lr;
        const float bn = bias[n];
#pragma unroll
        for (int mi = 0; mi < MF; ++mi) {
          const int mb = m0 + wr * WM + mi * 16 + lg * 4;
          ushort4 pk;
          pk.x = f2bf(acc[mi][ni][0] + bn);
          pk.y = f2bf(acc[mi][ni][1] + bn);
          pk.z = f2bf(acc[mi][ni][2] + bn);
          pk.w = f2bf(acc[mi][ni][3] + bn);
          *reinterpret_cast<ushort4*>(&outv[(size_t)(n - 2048) * M + mb]) = pk;
        }
      }
    }
  }
}

// ---------------- flash attention, KV-split, fixed-shift softmax ------------
// qk: [2048][2048] bf16 (q|k). vt: [1024][2048] bf16 (V^T).
// Opart: [KSPLIT][2048][1024] bf16. lsum: [KSPLIT][16][2048] f32.
// In-register P (K=16 A-frag match); row-sum l computed by a ones-column
// MFMA on the matrix pipe (replaces 16 VALU adds/tile/lane).
template <int KSPLIT>
__global__ __launch_bounds__(256)
void k_attn(const u16* __restrict__ qk, const u16* __restrict__ vt,
            u16* __restrict__ Opart, float* __restrict__ lsum_out) {
  __shared__ u16 Klds[2][64 * 64];
  __shared__ u16 Vlds[2][64 * 64];
  const int tid = threadIdx.x;
  const int w = tid >> 6, l = tid & 63, lg = l >> 4, lr = l & 15;

  // bijective remap of (qb, h, sp): XCD k -> heads {2k, 2k+1}
  const int u = blockIdx.x + 32 * (blockIdx.y + NH * blockIdx.z);
  const int xcd = u & 7, g = u >> 3;      // g in [0, 64*KSPLIT)
  const int h = 2 * xcd + (g / (32 * KSPLIT));
  const int rem = g % (32 * KSPLIT);
  const int sp = rem >> 5;
  const int qb = rem & 31;

  constexpr int NT = (SEQ / 64) / KSPLIT;
  const int kb0 = sp * NT;

  // Q B-fragment: lane holds Q[q=lr][d = half*32 + lg*8 + j]
  bf16x8 qf[2];
  {
    const size_t qrow = (size_t)(qb * 64 + w * 16 + lr) * 2048 + h * 64;
    qf[0] = *reinterpret_cast<const bf16x8*>(&qk[qrow + lg * 8]);
    qf[1] = *reinterpret_cast<const bf16x8*>(&qk[qrow + 32 + lg * 8]);
  }

  // staging: linear LDS dest (global_load_lds), inverse-swizzled global source
  const int sr0 = w * 16 + (l >> 3);
  const int sc0 = ((l & 7) ^ (sr0 & 7)) * 8;
  const int sr1 = sr0 + 8;
  const int sc1 = ((l & 7) ^ (sr1 & 7)) * 8;
  const u16* kb_base = qk + 1024 + h * 64;
  const u16* vb_base = vt + (size_t)(h * 64) * 2048;

  auto stage = [&](int buf, int kb) {
    const u16* k0 = kb_base + (size_t)(kb * 64 + sr0) * 2048 + sc0;
    const u16* k1 = kb_base + (size_t)(kb * 64 + sr1) * 2048 + sc1;
    const u16* v0 = vb_base + (size_t)sr0 * 2048 + kb * 64 + sc0;
    const u16* v1 = vb_base + (size_t)sr1 * 2048 + kb * 64 + sc1;
    GLD_LDS16(k0, &Klds[buf][(w * 16) * 64]);
    GLD_LDS16(k1, &Klds[buf][(w * 16 + 8) * 64]);
    GLD_LDS16(v0, &Vlds[buf][(w * 16) * 64]);
    GLD_LDS16(v1, &Vlds[buf][(w * 16 + 8) * 64]);
  };

  auto kread = [&](int buf, int row, int kbyte) -> bf16x8 {
    const int off = row * 128 + (kbyte ^ ((row & 7) << 4));
    return *reinterpret_cast<const bf16x8*>(
        reinterpret_cast<const char*>(&Klds[buf][0]) + off);
  };

  f32x4 oacc[4] = {};
  f32x4 lacc = {};                        // row-sums via ones-MFMA
  const float SC = 0.18033688011112042f;  // log2(e)/8
  const s16x4 ONES = {(short)0x3F80, (short)0x3F80, (short)0x3F80, (short)0x3F80};

  stage(0, kb0);
  __syncthreads();

  for (int t = 0; t < NT; ++t) {
    const int cur = t & 1;
    if (t + 1 < NT) stage(cur ^ 1, kb0 + t + 1);

    // swapped QK^T: lane: q=lr, kv = nt*16 + lg*4 + r
    float p[4][4];
    __builtin_amdgcn_s_setprio(1);
#pragma unroll
    for (int nt = 0; nt < 4; ++nt) {
      bf16x8 kf0 = kread(cur, nt * 16 + lr, lg * 16);
      bf16x8 kf1 = kread(cur, nt * 16 + lr, 64 + lg * 16);
      f32x4 a = {};
      a = __builtin_amdgcn_mfma_f32_16x16x32_bf16(kf0, qf[0], a, 0, 0, 0);
      a = __builtin_amdgcn_mfma_f32_16x16x32_bf16(kf1, qf[1], a, 0, 0, 0);
#pragma unroll
      for (int r = 0; r < 4; ++r)
        p[nt][r] = exp2f(fmaf(a[r], SC, -8.0f));
    }

    // PV: O[q][d] += P[q][kv] * V[kv][d]; l[q] += P[q][kv] * 1
#pragma unroll
    for (int nt = 0; nt < 4; ++nt) {
      union { u32 wd[2]; s16x4 v; } pa;
      pa.wd[0] = packbf(p[nt][0], p[nt][1]);
      pa.wd[1] = packbf(p[nt][2], p[nt][3]);
      lacc = mfma16x16x16bf(pa.v, ONES, lacc);
#pragma unroll
      for (int nd = 0; nd < 4; ++nd) {
        const int row = nd * 16 + lr;  // d row in V LDS tile
        const int off = row * 128 + ((nt * 32 + lg * 8) ^ ((row & 7) << 4));
        s16x4 vf = *reinterpret_cast<const s16x4*>(
            reinterpret_cast<const char*>(&Vlds[cur][0]) + off);
        oacc[nd] = mfma16x16x16bf(pa.v, vf, oacc[nd]);
      }
    }
    __builtin_amdgcn_s_setprio(0);
    __syncthreads();
  }

  // epilogue: unnormalized O (bf16); lacc[r] = l for q-row lg*4+r (all lr same)
#pragma unroll
  for (int r = 0; r < 4; ++r) {
    const size_t orow = (size_t)sp * SEQ * DM +
                        (size_t)(qb * 64 + w * 16 + lg * 4 + r) * DM + h * 64;
#pragma unroll
    for (int nd = 0; nd < 4; ++nd)
      Opart[orow + nd * 16 + lr] = f2bf(oacc[nd][r]);
  }
  if (lr == 0) {
#pragma unroll
    for (int r = 0; r < 4; ++r)
      lsum_out[((size_t)sp * NH + h) * SEQ + qb * 64 + w * 16 + lg * 4 + r] =
          lacc[r];
  }
}

// ---------------- combine KV-splits (same shift -> plain sum) ----------------
template <int KSPLIT>
__global__ __launch_bounds__(256)
void k_combine(const u16* __restrict__ Opart, const float* __restrict__ lsum,
               u16* __restrict__ attn_out) {
  const int row = blockIdx.x, tid = threadIdx.x;
  const int h = tid >> 4;
  float den = 0.f;
#pragma unroll
  for (int s = 0; s < KSPLIT; ++s)
    den += lsum[((size_t)s * NH + h) * SEQ + row];
  const float inv = 1.f / den;
  float o[4] = {0.f, 0.f, 0.f, 0.f};
#pragma unroll
  for (int s = 0; s < KSPLIT; ++s) {
    const ushort4 v = reinterpret_cast<const ushort4*>(
        Opart + ((size_t)s * SEQ + row) * DM)[tid];
    o[0] += bf2f(v.x); o[1] += bf2f(v.y);
    o[2] += bf2f(v.z); o[3] += bf2f(v.w);
  }
  ushort4 pk;
  pk.x = f2bf(o[0] * inv); pk.y = f2bf(o[1] * inv);
  pk.z = f2bf(o[2] * inv); pk.w = f2bf(o[3] * inv);
  reinterpret_cast<ushort4*>(attn_out + (size_t)row * DM)[tid] = pk;
}

// ---------------- fused split-K combine + residual + bias + LayerNorm -------
__global__ __launch_bounds__(256)
void k_ln(const float* __restrict__ hin, const u16* __restrict__ pp,
          const float* __restrict__ bout, const float* __restrict__ gamma,
          const float* __restrict__ beta, float* __restrict__ out) {
  const int row = blockIdx.x, tid = threadIdx.x;
  const float4 hv = reinterpret_cast<const float4*>(hin + (size_t)row * DM)[tid];
  const ushort4 p0 = reinterpret_cast<const ushort4*>(pp + (size_t)row * DM)[tid];
  const ushort4 p1 = reinterpret_cast<const ushort4*>(pp + (size_t)(SEQ + row) * DM)[tid];
  const float4 bv = reinterpret_cast<const float4*>(bout)[tid];
  float4 v;
  v.x = hv.x + bf2f(p0.x) + bf2f(p1.x) + bv.x;
  v.y = hv.y + bf2f(p0.y) + bf2f(p1.y) + bv.y;
  v.z = hv.z + bf2f(p0.z) + bf2f(p1.z) + bv.z;
  v.w = hv.w + bf2f(p0.w) + bf2f(p1.w) + bv.w;
  float s = v.x + v.y + v.z + v.w;
  float q = v.x * v.x + v.y * v.y + v.z * v.z + v.w * v.w;
#pragma unroll
  for (int m = 1; m < 64; m <<= 1) { s += __shfl_xor(s, m); q += __shfl_xor(q, m); }
  __shared__ float sh[8];
  const int w = tid >> 6;
  if ((tid & 63) == 0) { sh[w] = s; sh[4 + w] = q; }
  __syncthreads();
  s = sh[0] + sh[1] + sh[2] + sh[3];
  q = sh[4] + sh[5] + sh[6] + sh[7];
  const float mu = s * (1.f / 1024.f);
  const float var = q * (1.f / 1024.f) - mu * mu;
  const float rstd = rsqrtf(var + LN_EPS);
  float4 g = reinterpret_cast<const float4*>(gamma)[tid];
  float4 b = reinterpret_cast<const float4*>(beta)[tid];
  float4 o;
  o.x = (v.x - mu) * rstd * g.x + b.x;
  o.y = (v.y - mu) * rstd * g.y + b.y;
  o.z = (v.z - mu) * rstd * g.z + b.z;
  o.w = (v.w - mu) * rstd * g.w + b.w;
  reinterpret_cast<float4*>(out + (size_t)row * DM)[tid] = o;
}

extern "C" void kernel_launch(void* const* d_in, const int* in_sizes, int n_in,
                              void* d_out, int out_size, void* d_ws, size_t ws_size,
                              hipStream_t stream) {
  const float* h     = (const float*)d_in[0];
  const float* Wqkv  = (const float*)d_in[1];
  const float* bqkv  = (const float*)d_in[2];
  const float* Wout  = (const float*)d_in[3];
  const float* bout  = (const float*)d_in[4];
  const float* gamma = (const float*)d_in[5];
  const float* beta  = (const float*)d_in[6];
  float* out = (float*)d_out;

  char* ws = (char*)d_ws;
  u16* h_bf      = (u16*)(ws);                              // 4 MB
  u16* Wqkv_bf   = (u16*)(ws + (size_t)4 * 1024 * 1024);    // 6 MB
  u16* Wout_bf   = (u16*)(ws + (size_t)10 * 1024 * 1024);   // 2 MB
  u16* qk_bf     = (u16*)(ws + (size_t)12 * 1024 * 1024);   // 8 MB
  u16* vt_bf     = (u16*)(ws + (size_t)20 * 1024 * 1024);   // 4 MB
  u16* attn_bf   = (u16*)(ws + (size_t)24 * 1024 * 1024);   // 4 MB
  u16* Opart     = (u16*)(ws + (size_t)28 * 1024 * 1024);   // 16 MB (4 splits bf16)
  u16* Opp       = (u16*)(ws + (size_t)44 * 1024 * 1024);   // 8 MB (2 splits bf16)
  float* lsums   = (float*)(ws + (size_t)52 * 1024 * 1024); // 0.5 MB

  const int na = SEQ * DM / 4, nb = 3 * DM * DM / 4, nc = DM * DM / 4;
  k_f2bf3<<<(na + nb + nc + 255) / 256, 256, 0, stream>>>(
      h, h_bf, na, Wqkv, Wqkv_bf, nb, Wout, Wout_bf, nc);

  k_gemm_bt<2, 64, 128, 3><<<dim3(24, 32), 256, 0, stream>>>(
      h_bf, Wqkv_bf, bqkv, qk_bf, vt_bf, SEQ, 3 * DM, DM);

  k_attn<4><<<dim3(SEQ / 64, NH, 4), 256, 0, stream>>>(qk_bf, vt_bf, Opart, lsums);
  k_combine<4><<<SEQ, 256, 0, stream>>>(Opart, lsums, attn_bf);

  k_gemm_bt<3, 64, 64, 2><<<dim3(16, 32, 2), 256, 0, stream>>>(
      attn_bf, Wout_bf, nullptr, Opp, nullptr, SEQ, DM, DM);

  k_ln<<<SEQ, 256, 0, stream>>>(h, Opp, bout, gamma, beta, out);
}

// Round 10
// 94.461 us; speedup vs baseline: 1.0203x; 1.0203x over previous
//
#include <hip/hip_runtime.h>
#include <stdint.h>

#define SEQ 2048
#define DM 1024
#define NH 16
#define DH 64
#define LN_EPS 1e-5f

typedef __bf16 bf16x8 __attribute__((ext_vector_type(8)));
typedef float f32x4 __attribute__((ext_vector_type(4)));
typedef unsigned short u16;
typedef unsigned short u16x8 __attribute__((ext_vector_type(8)));
typedef unsigned int u32;
typedef short s16x4 __attribute__((ext_vector_type(4)));

__device__ __forceinline__ u16 f2bf(float f) {
  unsigned int u = __float_as_uint(f);
  unsigned int r = (u + 0x7fffu + ((u >> 16) & 1u)) >> 16;
  return (u16)r;
}

__device__ __forceinline__ float bf2f(u16 x) {
  return __uint_as_float(((u32)x) << 16);
}

__device__ __forceinline__ u32 packbf(float a, float b) {
  union { __bf16 h[2]; u32 u; } pw;
  pw.h[0] = (__bf16)a; pw.h[1] = (__bf16)b;
  return pw.u;
}

// 16x16x16 bf16 MFMA (2-reg A/B).
__device__ __forceinline__ f32x4 mfma16x16x16bf(s16x4 a, s16x4 b, f32x4 c) {
#if __has_builtin(__builtin_amdgcn_mfma_f32_16x16x16bf16_1k)
  return __builtin_amdgcn_mfma_f32_16x16x16bf16_1k(a, b, c, 0, 0, 0);
#else
  asm("v_mfma_f32_16x16x16_bf16 %0, %1, %2, %0" : "+v"(c) : "v"(a), "v"(b));
  return c;
#endif
}

#define GLD_LDS16(gp, lp) __builtin_amdgcn_global_load_lds( \
  (const __attribute__((address_space(1))) void*)(gp),      \
  (__attribute__((address_space(3))) void*)(lp), 16, 0, 0)

// ---------------- fused f32 -> bf16 convert (h, Wqkv, Wout in one launch) ----
__global__ __launch_bounds__(256)
void k_f2bf3(const float* __restrict__ a, u16* __restrict__ oa, int na,
             const float* __restrict__ b, u16* __restrict__ ob, int nb,
             const float* __restrict__ c, u16* __restrict__ oc, int nc) {
  int i = blockIdx.x * 256 + threadIdx.x;
  const float* src;
  u16* dst;
  if (i < na) { src = a; dst = oa; }
  else if (i < na + nb) { src = b; dst = ob; i -= na; }
  else if (i < na + nb + nc) { src = c; dst = oc; i -= na + nb; }
  else return;
  float4 v = reinterpret_cast<const float4*>(src)[i];
  ushort4 o;
  o.x = f2bf(v.x); o.y = f2bf(v.y); o.z = f2bf(v.z); o.w = f2bf(v.w);
  reinterpret_cast<ushort4*>(dst)[i] = o;
}

// ---------------- GEMM: C = A(bf16 MxK) * B(bf16 NxK)^T ----------------
template <int EPI, int BM, int BN, int XCDW>
__global__ __launch_bounds__(256)
void k_gemm_bt(const u16* __restrict__ A, const u16* __restrict__ B,
               const float* __restrict__ bias,
               u16* __restrict__ outb, u16* __restrict__ outv,
               int M, int N, int K) {
  constexpr int MF = BM / 32, NF = BN / 32;
  constexpr int WM = BM / 2, WN = BN / 2;
  constexpr int AG = BM / 64, BG = BN / 64;
  __shared__ u16 Alds[2][BM][32];
  __shared__ u16 Blds[2][BN][32];
  const int tid = threadIdx.x;
  const int w = tid >> 6, l = tid & 63, lg = l >> 4, lr = l & 15;
  const int wr = w >> 1, wc = w & 1;

  int bx = blockIdx.x, by = blockIdx.y, bz = blockIdx.z;
  if (XCDW > 0) {
    const int nx = gridDim.x, ny = gridDim.y;
    const int u = bx + nx * (by + ny * bz);
    const int xcd = u & 7, g = u >> 3;
    bx = xcd * XCDW + (g % XCDW);
    const int rem = g / XCDW;
    by = rem % ny;
    bz = rem / ny;
  }

  const int m0 = by * BM, n0 = bx * BN;
  const int KTall = K >> 5;
  const int ktn = KTall / gridDim.z;
  const int kt0 = bz * ktn;

  f32x4 acc[MF][NF] = {};

  auto stage = [&](int buf, int kt) {
    const int k0 = kt << 5;
    const int row = l >> 2, col = (l & 3) * 8;
#pragma unroll
    for (int p = 0; p < AG; ++p) {
      const int rbase = (w * AG + p) * 16;
      GLD_LDS16(A + (size_t)(m0 + rbase + row) * K + k0 + col, &Alds[buf][rbase][0]);
    }
#pragma unroll
    for (int p = 0; p < BG; ++p) {
      const int rbase = (w * BG + p) * 16;
      GLD_LDS16(B + (size_t)(n0 + rbase + row) * K + k0 + col, &Blds[buf][rbase][0]);
    }
  };

  auto compute = [&](int buf) {
    bf16x8 af[MF], bfr[NF];
#pragma unroll
    for (int mi = 0; mi < MF; ++mi)
      af[mi] = *reinterpret_cast<const bf16x8*>(&Alds[buf][wr * WM + mi * 16 + lr][lg * 8]);
#pragma unroll
    for (int ni = 0; ni < NF; ++ni)
      bfr[ni] = *reinterpret_cast<const bf16x8*>(&Blds[buf][wc * WN + ni * 16 + lr][lg * 8]);
#pragma unroll
    for (int mi = 0; mi < MF; ++mi)
#pragma unroll
      for (int ni = 0; ni < NF; ++ni)
        acc[mi][ni] = __builtin_amdgcn_mfma_f32_16x16x32_bf16(af[mi], bfr[ni], acc[mi][ni], 0, 0, 0);
  };

  stage(0, kt0);
  __syncthreads();
  for (int i = 0; i < ktn; ++i) {
    const int cur = i & 1;
    if (i + 1 < ktn) stage(cur ^ 1, kt0 + i + 1);
    compute(cur);
    __syncthreads();
  }

  if (EPI == 3) {
    u16* op = outb + (size_t)bz * M * N;
#pragma unroll
    for (int ni = 0; ni < NF; ++ni) {
      const int n = n0 + wc * WN + ni * 16 + lr;
#pragma unroll
      for (int mi = 0; mi < MF; ++mi) {
#pragma unroll
        for (int r = 0; r < 4; ++r) {
          const int m = m0 + wr * WM + mi * 16 + lg * 4 + r;
          op[(size_t)m * N + n] = f2bf(acc[mi][ni][r]);
        }
      }
    }
  } else {  // EPI == 2
    if (n0 < 2048) {
#pragma unroll
      for (int ni = 0; ni < NF; ++ni) {
        const int n = n0 + wc * WN + ni * 16 + lr;
        const float bn = bias[n];
#pragma unroll
        for (int mi = 0; mi < MF; ++mi) {
#pragma unroll
          for (int r = 0; r < 4; ++r) {
            const int m = m0 + wr * WM + mi * 16 + lg * 4 + r;
            outb[(size_t)m * 2048 + n] = f2bf(acc[mi][ni][r] + bn);
          }
        }
      }
    } else {
#pragma unroll
      for (int ni = 0; ni < NF; ++ni) {
        const int n = n0 + wc * WN + ni * 16 + lr;
        const float bn = bias[n];
#pragma unroll
        for (int mi = 0; mi < MF; ++mi) {
          const int mb = m0 + wr * WM + mi * 16 + lg * 4;
          ushort4 pk;
          pk.x = f2bf(acc[mi][ni][0] + bn);
          pk.y = f2bf(acc[mi][ni][1] + bn);
          pk.z = f2bf(acc[mi][ni][2] + bn);
          pk.w = f2bf(acc[mi][ni][3] + bn);
          *reinterpret_cast<ushort4*>(&outv[(size_t)(n - 2048) * M + mb]) = pk;
        }
      }
    }
  }
}

// ---------------- flash attention: 128 q-rows/block, KV-split, fixed shift --
// qk: [2048][2048] bf16 (q|k). vt: [1024][2048] bf16 (V^T).
// Opart: [KSPLIT][2048][1024] bf16. lsum: [KSPLIT][16][2048] f32.
// Each wave owns TWO 16-row q groups (A at +0, B at +64) so every K/V LDS
// read feeds 2 MFMAs -> LDS bytes per FLOP halved vs 64-row blocks.
template <int KSPLIT>
__global__ __launch_bounds__(256)
void k_attn(const u16* __restrict__ qk, const u16* __restrict__ vt,
            u16* __restrict__ Opart, float* __restrict__ lsum_out) {
  __shared__ u16 Klds[2][64 * 64];
  __shared__ u16 Vlds[2][64 * 64];
  const int tid = threadIdx.x;
  const int w = tid >> 6, l = tid & 63, lg = l >> 4, lr = l & 15;

  // bijective remap of (qb2, h, sp): XCD k -> heads {2k, 2k+1}
  const int u = blockIdx.x + 16 * (blockIdx.y + NH * blockIdx.z);
  const int xcd = u & 7, g = u >> 3;      // g in [0, 32*KSPLIT)
  const int h = 2 * xcd + (g / (16 * KSPLIT));
  const int rem = g % (16 * KSPLIT);
  const int sp = rem >> 4;
  const int qb2 = rem & 15;               // 128-row q block

  constexpr int NT = (SEQ / 64) / KSPLIT;
  const int kb0 = sp * NT;

  // Q B-fragments for both 16-row groups
  bf16x8 qfA[2], qfB[2];
  {
    const size_t qrowA = (size_t)(qb2 * 128 + w * 16 + lr) * 2048 + h * 64;
    qfA[0] = *reinterpret_cast<const bf16x8*>(&qk[qrowA + lg * 8]);
    qfA[1] = *reinterpret_cast<const bf16x8*>(&qk[qrowA + 32 + lg * 8]);
    const size_t qrowB = qrowA + (size_t)64 * 2048;
    qfB[0] = *reinterpret_cast<const bf16x8*>(&qk[qrowB + lg * 8]);
    qfB[1] = *reinterpret_cast<const bf16x8*>(&qk[qrowB + 32 + lg * 8]);
  }

  // staging: linear LDS dest (global_load_lds), inverse-swizzled global source
  const int sr0 = w * 16 + (l >> 3);
  const int sc0 = ((l & 7) ^ (sr0 & 7)) * 8;
  const int sr1 = sr0 + 8;
  const int sc1 = ((l & 7) ^ (sr1 & 7)) * 8;
  const u16* kb_base = qk + 1024 + h * 64;
  const u16* vb_base = vt + (size_t)(h * 64) * 2048;

  auto stage = [&](int buf, int kb) {
    const u16* k0 = kb_base + (size_t)(kb * 64 + sr0) * 2048 + sc0;
    const u16* k1 = kb_base + (size_t)(kb * 64 + sr1) * 2048 + sc1;
    const u16* v0 = vb_base + (size_t)sr0 * 2048 + kb * 64 + sc0;
    const u16* v1 = vb_base + (size_t)sr1 * 2048 + kb * 64 + sc1;
    GLD_LDS16(k0, &Klds[buf][(w * 16) * 64]);
    GLD_LDS16(k1, &Klds[buf][(w * 16 + 8) * 64]);
    GLD_LDS16(v0, &Vlds[buf][(w * 16) * 64]);
    GLD_LDS16(v1, &Vlds[buf][(w * 16 + 8) * 64]);
  };

  auto kread = [&](int buf, int row, int kbyte) -> bf16x8 {
    const int off = row * 128 + (kbyte ^ ((row & 7) << 4));
    return *reinterpret_cast<const bf16x8*>(
        reinterpret_cast<const char*>(&Klds[buf][0]) + off);
  };

  f32x4 oaccA[4] = {}, oaccB[4] = {};
  f32x4 laccA = {}, laccB = {};
  const float SC = 0.18033688011112042f;  // log2(e)/8
  const s16x4 ONES = {(short)0x3F80, (short)0x3F80, (short)0x3F80, (short)0x3F80};

  stage(0, kb0);
  __syncthreads();

  for (int t = 0; t < NT; ++t) {
    const int cur = t & 1;
    if (t + 1 < NT) stage(cur ^ 1, kb0 + t + 1);

    // swapped QK^T for both groups; K frags shared
    u32 pawA[4][2], pawB[4][2];
    __builtin_amdgcn_s_setprio(1);
#pragma unroll
    for (int nt = 0; nt < 4; ++nt) {
      bf16x8 kf0 = kread(cur, nt * 16 + lr, lg * 16);
      bf16x8 kf1 = kread(cur, nt * 16 + lr, 64 + lg * 16);
      f32x4 aA = {}, aB = {};
      aA = __builtin_amdgcn_mfma_f32_16x16x32_bf16(kf0, qfA[0], aA, 0, 0, 0);
      aA = __builtin_amdgcn_mfma_f32_16x16x32_bf16(kf1, qfA[1], aA, 0, 0, 0);
      aB = __builtin_amdgcn_mfma_f32_16x16x32_bf16(kf0, qfB[0], aB, 0, 0, 0);
      aB = __builtin_amdgcn_mfma_f32_16x16x32_bf16(kf1, qfB[1], aB, 0, 0, 0);
      float pA[4], pB[4];
#pragma unroll
      for (int r = 0; r < 4; ++r) {
        pA[r] = exp2f(fmaf(aA[r], SC, -8.0f));
        pB[r] = exp2f(fmaf(aB[r], SC, -8.0f));
      }
      pawA[nt][0] = packbf(pA[0], pA[1]);
      pawA[nt][1] = packbf(pA[2], pA[3]);
      pawB[nt][0] = packbf(pB[0], pB[1]);
      pawB[nt][1] = packbf(pB[2], pB[3]);
    }

    // PV + row-sums; V frags shared between groups
#pragma unroll
    for (int nt = 0; nt < 4; ++nt) {
      union { u32 wd[2]; s16x4 v; } paA, paB;
      paA.wd[0] = pawA[nt][0]; paA.wd[1] = pawA[nt][1];
      paB.wd[0] = pawB[nt][0]; paB.wd[1] = pawB[nt][1];
      laccA = mfma16x16x16bf(paA.v, ONES, laccA);
      laccB = mfma16x16x16bf(paB.v, ONES, laccB);
#pragma unroll
      for (int nd = 0; nd < 4; ++nd) {
        const int row = nd * 16 + lr;
        const int off = row * 128 + ((nt * 32 + lg * 8) ^ ((row & 7) << 4));
        s16x4 vf = *reinterpret_cast<const s16x4*>(
            reinterpret_cast<const char*>(&Vlds[cur][0]) + off);
        oaccA[nd] = mfma16x16x16bf(paA.v, vf, oaccA[nd]);
        oaccB[nd] = mfma16x16x16bf(paB.v, vf, oaccB[nd]);
      }
    }
    __builtin_amdgcn_s_setprio(0);
    __syncthreads();
  }

  // epilogue: unnormalized O (bf16) + per-row l for both groups
  const size_t obase = (size_t)sp * SEQ * DM;
#pragma unroll
  for (int r = 0; r < 4; ++r) {
    const size_t qA = qb2 * 128 + w * 16 + lg * 4 + r;
    const size_t rowA = obase + qA * DM + h * 64;
    const size_t rowB = rowA + (size_t)64 * DM;
#pragma unroll
    for (int nd = 0; nd < 4; ++nd) {
      Opart[rowA + nd * 16 + lr] = f2bf(oaccA[nd][r]);
      Opart[rowB + nd * 16 + lr] = f2bf(oaccB[nd][r]);
    }
  }
  if (lr == 0) {
    const size_t lbase = ((size_t)sp * NH + h) * SEQ + qb2 * 128 + w * 16;
#pragma unroll
    for (int r = 0; r < 4; ++r) {
      lsum_out[lbase + lg * 4 + r] = laccA[r];
      lsum_out[lbase + 64 + lg * 4 + r] = laccB[r];
    }
  }
}

// ---------------- combine KV-splits (same shift -> plain sum) ----------------
template <int KSPLIT>
__global__ __launch_bounds__(256)
void k_combine(const u16* __restrict__ Opart, const float* __restrict__ lsum,
               u16* __restrict__ attn_out) {
  const int row = blockIdx.x, tid = threadIdx.x;
  const int h = tid >> 4;
  float den = 0.f;
#pragma unroll
  for (int s = 0; s < KSPLIT; ++s)
    den += lsum[((size_t)s * NH + h) * SEQ + row];
  const float inv = 1.f / den;
  float o[4] = {0.f, 0.f, 0.f, 0.f};
#pragma unroll
  for (int s = 0; s < KSPLIT; ++s) {
    const ushort4 v = reinterpret_cast<const ushort4*>(
        Opart + ((size_t)s * SEQ + row) * DM)[tid];
    o[0] += bf2f(v.x); o[1] += bf2f(v.y);
    o[2] += bf2f(v.z); o[3] += bf2f(v.w);
  }
  ushort4 pk;
  pk.x = f2bf(o[0] * inv); pk.y = f2bf(o[1] * inv);
  pk.z = f2bf(o[2] * inv); pk.w = f2bf(o[3] * inv);
  reinterpret_cast<ushort4*>(attn_out + (size_t)row * DM)[tid] = pk;
}

// ---------------- fused split-K combine + residual + bias + LayerNorm -------
__global__ __launch_bounds__(256)
void k_ln(const float* __restrict__ hin, const u16* __restrict__ pp,
          const float* __restrict__ bout, const float* __restrict__ gamma,
          const float* __restrict__ beta, float* __restrict__ out) {
  const int row = blockIdx.x, tid = threadIdx.x;
  const float4 hv = reinterpret_cast<const float4*>(hin + (size_t)row * DM)[tid];
  const ushort4 p0 = reinterpret_cast<const ushort4*>(pp + (size_t)row * DM)[tid];
  const ushort4 p1 = reinterpret_cast<const ushort4*>(pp + (size_t)(SEQ + row) * DM)[tid];
  const float4 bv = reinterpret_cast<const float4*>(bout)[tid];
  float4 v;
  v.x = hv.x + bf2f(p0.x) + bf2f(p1.x) + bv.x;
  v.y = hv.y + bf2f(p0.y) + bf2f(p1.y) + bv.y;
  v.z = hv.z + bf2f(p0.z) + bf2f(p1.z) + bv.z;
  v.w = hv.w + bf2f(p0.w) + bf2f(p1.w) + bv.w;
  float s = v.x + v.y + v.z + v.w;
  float q = v.x * v.x + v.y * v.y + v.z * v.z + v.w * v.w;
#pragma unroll
  for (int m = 1; m < 64; m <<= 1) { s += __shfl_xor(s, m); q += __shfl_xor(q, m); }
  __shared__ float sh[8];
  const int w = tid >> 6;
  if ((tid & 63) == 0) { sh[w] = s; sh[4 + w] = q; }
  __syncthreads();
  s = sh[0] + sh[1] + sh[2] + sh[3];
  q = sh[4] + sh[5] + sh[6] + sh[7];
  const float mu = s * (1.f / 1024.f);
  const float var = q * (1.f / 1024.f) - mu * mu;
  const float rstd = rsqrtf(var + LN_EPS);
  float4 g = reinterpret_cast<const float4*>(gamma)[tid];
  float4 b = reinterpret_cast<const float4*>(beta)[tid];
  float4 o;
  o.x = (v.x - mu) * rstd * g.x + b.x;
  o.y = (v.y - mu) * rstd * g.y + b.y;
  o.z = (v.z - mu) * rstd * g.z + b.z;
  o.w = (v.w - mu) * rstd * g.w + b.w;
  reinterpret_cast<float4*>(out + (size_t)row * DM)[tid] = o;
}

extern "C" void kernel_launch(void* const* d_in, const int* in_sizes, int n_in,
                              void* d_out, int out_size, void* d_ws, size_t ws_size,
                              hipStream_t stream) {
  const float* h     = (const float*)d_in[0];
  const float* Wqkv  = (const float*)d_in[1];
  const float* bqkv  = (const float*)d_in[2];
  const float* Wout  = (const float*)d_in[3];
  const float* bout  = (const float*)d_in[4];
  const float* gamma = (const float*)d_in[5];
  const float* beta  = (const float*)d_in[6];
  float* out = (float*)d_out;

  char* ws = (char*)d_ws;
  u16* h_bf      = (u16*)(ws);                              // 4 MB
  u16* Wqkv_bf   = (u16*)(ws + (size_t)4 * 1024 * 1024);    // 6 MB
  u16* Wout_bf   = (u16*)(ws + (size_t)10 * 1024 * 1024);   // 2 MB
  u16* qk_bf     = (u16*)(ws + (size_t)12 * 1024 * 1024);   // 8 MB
  u16* vt_bf     = (u16*)(ws + (size_t)20 * 1024 * 1024);   // 4 MB
  u16* attn_bf   = (u16*)(ws + (size_t)24 * 1024 * 1024);   // 4 MB
  u16* Opart     = (u16*)(ws + (size_t)28 * 1024 * 1024);   // 16 MB (4 splits bf16)
  u16* Opp       = (u16*)(ws + (size_t)44 * 1024 * 1024);   // 8 MB (2 splits bf16)
  float* lsums   = (float*)(ws + (size_t)52 * 1024 * 1024); // 0.5 MB

  const int na = SEQ * DM / 4, nb = 3 * DM * DM / 4, nc = DM * DM / 4;
  k_f2bf3<<<(na + nb + nc + 255) / 256, 256, 0, stream>>>(
      h, h_bf, na, Wqkv, Wqkv_bf, nb, Wout, Wout_bf, nc);

  k_gemm_bt<2, 64, 128, 3><<<dim3(24, 32), 256, 0, stream>>>(
      h_bf, Wqkv_bf, bqkv, qk_bf, vt_bf, SEQ, 3 * DM, DM);

  k_attn<4><<<dim3(16, 16, 4), 256, 0, stream>>>(qk_bf, vt_bf, Opart, lsums);
  k_combine<4><<<SEQ, 256, 0, stream>>>(Opart, lsums, attn_bf);

  k_gemm_bt<3, 64, 64, 2><<<dim3(16, 32, 2), 256, 0, stream>>>(
      attn_bf, Wout_bf, nullptr, Opp, nullptr, SEQ, DM, DM);

  k_ln<<<SEQ, 256, 0, stream>>>(h, Opp, bout, gamma, beta, out);
}